// Round 9
// baseline (580.671 us; speedup 1.0000x reference)
//
#include <hip/hip_runtime.h>
#include <hip/hip_bf16.h>
#include <cstdint>

typedef unsigned short u16;
typedef unsigned int   u32;

typedef __attribute__((ext_vector_type(8))) short short8;   // 8 x bf16 (4 VGPRs)
typedef __attribute__((ext_vector_type(4))) float f32x4;    // MFMA accumulator

__device__ __forceinline__ float b2f(u16 v) { return __uint_as_float(((u32)v) << 16); }
__device__ __forceinline__ u16 f2b(float f) {
    u32 u = __float_as_uint(f);
    u += 0x7FFFu + ((u >> 16) & 1u);   // round-to-nearest-even
    return (u16)(u >> 16);
}

#define G2L16(gp, lp) __builtin_amdgcn_global_load_lds(                       \
    (const __attribute__((address_space(1))) void*)(gp),                      \
    (__attribute__((address_space(3))) void*)(lp), 16, 0, 0)

#define GRID_BLOCKS 512u

// ---------------------------------------------------------------------------
// Manual grid barrier: monotone counter, agent-scope atomics (cross-XCD safe).
// __syncthreads drains the block's writes (vmcnt 0) before lane0 releases.
// ---------------------------------------------------------------------------
__device__ __forceinline__ void grid_barrier(u32* bar, u32 target) {
    __syncthreads();
    if (threadIdx.x == 0) {
        __hip_atomic_fetch_add(bar, 1u, __ATOMIC_ACQ_REL, __HIP_MEMORY_SCOPE_AGENT);
        while (__hip_atomic_load(bar, __ATOMIC_ACQUIRE, __HIP_MEMORY_SCOPE_AGENT) < target)
            __builtin_amdgcn_s_sleep(2);
    }
    __syncthreads();
}

// ---------------------------------------------------------------------------
// f32 -> bf16 transpose tile body (32x32), LDS-staged
// ---------------------------------------------------------------------------
__device__ __forceinline__ void transpose_body(const float* __restrict__ in,
                                               u16* __restrict__ out,
                                               int R, int C, int lb, int tilesX,
                                               float (*tile)[33]) {
    const int bx = (lb % tilesX) * 32;
    const int by = (lb / tilesX) * 32;
    const int tx = threadIdx.x & 31, ty = threadIdx.x >> 5;   // 32 x 8
    #pragma unroll
    for (int i = 0; i < 32; i += 8)
        tile[ty + i][tx] = in[(size_t)(by + ty + i) * C + (bx + tx)];
    __syncthreads();
    #pragma unroll
    for (int i = 0; i < 32; i += 8)
        out[(size_t)(bx + ty + i) * R + (by + tx)] = f2b(tile[tx][ty + i]);
}

// ---------------------------------------------------------------------------
// MFMA GEMM body, BK=64, 8-slot XOR-swizzled LDS (round-4 measured config).
// 128x128 tile at (m0,n0), 4 waves, 4x4 16x16x32 frags.  EPI: 0 relu, 1 none.
// ---------------------------------------------------------------------------
template <int EPI>
__device__ void gemm_body(const u16* __restrict__ A, const u16* __restrict__ Bt,
                          const float* __restrict__ bias, u16* __restrict__ C,
                          int N, int K, int m0, int n0, char* smemraw) {
    u16* As = (u16*)smemraw;               // 128 x 64 bf16 = 16KB
    u16* Bs = (u16*)(smemraw + 16384);     // 128 x 64 bf16 = 16KB

    const int tid  = threadIdx.x;
    const int wave = tid >> 6, lane = tid & 63;
    const int wm   = (wave & 1) << 6;
    const int wn   = (wave >> 1) << 6;
    const int quad = lane >> 4, l16 = lane & 15;

    f32x4 acc[4][4];
    #pragma unroll
    for (int i = 0; i < 4; ++i)
        #pragma unroll
        for (int j = 0; j < 4; ++j) acc[i][j] = (f32x4){0.f, 0.f, 0.f, 0.f};

    int oo[4], rr[4], qq[4];
    #pragma unroll
    for (int j = 0; j < 4; ++j) {
        oo[j] = tid * 16 + j * 4096;
        rr[j] = oo[j] >> 7;
        qq[j] = ((oo[j] >> 4) & 7) ^ (rr[j] & 7);
    }

    const int ktiles = K >> 6;
    for (int kt = 0; kt < ktiles; ++kt) {
        const int kb = kt << 6;
        #pragma unroll
        for (int j = 0; j < 4; ++j) {
            G2L16((const char*)A  + ((size_t)(m0 + rr[j]) * K + kb) * 2 + qq[j] * 16,
                  (char*)As + oo[j]);
            G2L16((const char*)Bt + ((size_t)(n0 + rr[j]) * K + kb) * 2 + qq[j] * 16,
                  (char*)Bs + oo[j]);
        }
        __syncthreads();

        #pragma unroll
        for (int h = 0; h < 2; ++h) {
            short8 af[4], bf[4];
            #pragma unroll
            for (int mi = 0; mi < 4; ++mi) {
                const int R = wm + mi * 16 + l16;
                af[mi] = *(const short8*)(As + R * 64 + ((((h << 2) | quad) ^ (R & 7)) << 3));
            }
            #pragma unroll
            for (int ni = 0; ni < 4; ++ni) {
                const int R = wn + ni * 16 + l16;
                bf[ni] = *(const short8*)(Bs + R * 64 + ((((h << 2) | quad) ^ (R & 7)) << 3));
            }
            #pragma unroll
            for (int mi = 0; mi < 4; ++mi)
                #pragma unroll
                for (int ni = 0; ni < 4; ++ni)
                    acc[mi][ni] = __builtin_amdgcn_mfma_f32_16x16x32_bf16(
                        af[mi], bf[ni], acc[mi][ni], 0, 0, 0);
        }
        __syncthreads();
    }

    #pragma unroll
    for (int ni = 0; ni < 4; ++ni) {
        const int col = n0 + wn + ni * 16 + l16;
        const float bv = bias[col];
        #pragma unroll
        for (int mi = 0; mi < 4; ++mi) {
            const int row0 = m0 + wm + mi * 16 + quad * 4;
            #pragma unroll
            for (int r = 0; r < 4; ++r) {
                float v = acc[mi][ni][r] + bv;
                if (EPI == 0) v = fmaxf(v, 0.f);
                C[(size_t)(row0 + r) * N + col] = f2b(v);
            }
        }
    }
}

// ---------------------------------------------------------------------------
// Fused gate GEMM body: BK=32, dual page in-register, 2-row-group XOR swizzle
// (round-6 measured config, 0 conflicts).
// ---------------------------------------------------------------------------
__device__ void gate_body(const u16* __restrict__ iQb, const u16* __restrict__ ffn,
                          const u16* __restrict__ Wgt, const float* __restrict__ bg,
                          const float* __restrict__ iQ, float* __restrict__ out,
                          int m0, int n0, char* smemraw) {
    u16* As  = (u16*)smemraw;                // 128 x 32 = 8KB
    u16* Bs0 = (u16*)(smemraw + 8192);
    u16* Bs1 = (u16*)(smemraw + 16384);

    const int tid  = threadIdx.x;
    const int wave = tid >> 6, lane = tid & 63;
    const int wm   = (wave & 1) << 6;
    const int wn   = (wave >> 1) << 6;
    const int quad = lane >> 4, l16 = lane & 15;
    const int D = 1024, D2 = 2048;

    f32x4 acc[2][4][4];
    #pragma unroll
    for (int p = 0; p < 2; ++p)
        #pragma unroll
        for (int i = 0; i < 4; ++i)
            #pragma unroll
            for (int j = 0; j < 4; ++j) acc[p][i][j] = (f32x4){0.f, 0.f, 0.f, 0.f};

    int oo[2], grow[2], gcol[2];
    #pragma unroll
    for (int j = 0; j < 2; ++j) {
        oo[j] = tid * 16 + j * 4096;
        const int rp = oo[j] >> 7;              // row-group 0..63
        const int s  = (oo[j] >> 4) & 7;        // slot in group
        const int ch = s ^ (rp & 7);            // global chunk 0..7
        grow[j] = rp * 2 + (ch >> 2);           // global row 0..127
        gcol[j] = (ch & 3) * 16;                // byte offset in 64B k-window
    }

    const int ktiles = D2 >> 5;                 // 64
    for (int kt = 0; kt < ktiles; ++kt) {
        const int kb = kt << 5;
        const char* Ab = (const char*)((kb < D) ? (iQb + kb) : (ffn + (kb - D)));
        const char* B0 = (const char*)(Wgt + (size_t)n0 * D2 + kb);
        const char* B1 = (const char*)(Wgt + (size_t)(n0 + D) * D2 + kb);
        #pragma unroll
        for (int j = 0; j < 2; ++j) {
            G2L16(Ab + (size_t)(m0 + grow[j]) * D * 2 + gcol[j], (char*)As  + oo[j]);
            G2L16(B0 + (size_t)grow[j] * D2 * 2 + gcol[j],       (char*)Bs0 + oo[j]);
            G2L16(B1 + (size_t)grow[j] * D2 * 2 + gcol[j],       (char*)Bs1 + oo[j]);
        }
        __syncthreads();

        short8 af[4], bf0[4], bf1[4];
        #pragma unroll
        for (int mi = 0; mi < 4; ++mi) {
            const int R = wm + mi * 16 + l16;
            const int so = (R >> 1) * 64 +
                           (((((R & 1) << 2) | quad) ^ ((R >> 1) & 7)) << 3);
            af[mi] = *(const short8*)(As + so);
        }
        #pragma unroll
        for (int ni = 0; ni < 4; ++ni) {
            const int R = wn + ni * 16 + l16;
            const int so = (R >> 1) * 64 +
                           (((((R & 1) << 2) | quad) ^ ((R >> 1) & 7)) << 3);
            bf0[ni] = *(const short8*)(Bs0 + so);
            bf1[ni] = *(const short8*)(Bs1 + so);
        }
        #pragma unroll
        for (int mi = 0; mi < 4; ++mi)
            #pragma unroll
            for (int ni = 0; ni < 4; ++ni) {
                acc[0][mi][ni] = __builtin_amdgcn_mfma_f32_16x16x32_bf16(
                    af[mi], bf0[ni], acc[0][mi][ni], 0, 0, 0);
                acc[1][mi][ni] = __builtin_amdgcn_mfma_f32_16x16x32_bf16(
                    af[mi], bf1[ni], acc[1][mi][ni], 0, 0, 0);
            }
        __syncthreads();
    }

    #pragma unroll
    for (int ni = 0; ni < 4; ++ni) {
        const int col = n0 + wn + ni * 16 + l16;
        const float bgi = bg[col];
        const float bgf = bg[col + D];
        #pragma unroll
        for (int mi = 0; mi < 4; ++mi) {
            const int row0 = m0 + wm + mi * 16 + quad * 4;
            #pragma unroll
            for (int r = 0; r < 4; ++r) {
                const size_t idx = (size_t)(row0 + r) * D + col;
                const float gi = 1.0f / (1.0f + __expf(-(acc[0][mi][ni][r] + bgi)));
                const float gf = 1.0f / (1.0f + __expf(-(acc[1][mi][ni][r] + bgf)));
                out[idx] = gi * iQ[idx] + gf * b2f(ffn[idx]);
            }
        }
    }
}

// ---------------------------------------------------------------------------
// Persistent fused kernel: 512 blocks x 256 thr, exactly 2 blocks/CU
// (LDS 32KB, __launch_bounds__(256,2)) -> all blocks co-resident.
// P0: weight transposes + 16-row chunk sums of iV
// P1: cumavg scan + iQ cast
// P2: h = relu(avg @ W1t^T + b1)
// P3: ffn = h @ W2t^T + b2   (ffn overlays avg)
// P4: fused gate GEMM + sigmoid + gate epilogue
// ---------------------------------------------------------------------------
__global__ __launch_bounds__(256, 2)
void fused_kernel(const float* __restrict__ iQ, const float* __restrict__ iV,
                  const float* __restrict__ W1, const float* __restrict__ b1,
                  const float* __restrict__ W2, const float* __restrict__ b2,
                  const float* __restrict__ Wg, const float* __restrict__ bg,
                  float* __restrict__ out,
                  u16* __restrict__ regA,   // avg -> ffn
                  u16* __restrict__ h,
                  u16* __restrict__ iQb,
                  u16* __restrict__ W1t, u16* __restrict__ W2t,
                  u16* __restrict__ Wgt, float* __restrict__ csum,
                  u32* __restrict__ bar) {
    __shared__ __align__(16) char smem[32768];
    const int bid = blockIdx.x;
    const int tid = threadIdx.x;

    // ---------------- P0: transposes + chunk sums ----------------
    {
        float (*tile)[33] = (float (*)[33])smem;
        for (int job = bid; job < 6144; job += GRID_BLOCKS) {   // 12 per block
            if (job < 1024)      transpose_body(W1, W1t, 1024, 1024, job, 32, tile);
            else if (job < 2048) transpose_body(W2, W2t, 1024, 1024, job - 1024, 32, tile);
            else                 transpose_body(Wg, Wgt, 2048, 2048, job - 2048, 64, tile);
            __syncthreads();
        }
        // chunk sums: one 16-row chunk per block (4 batches x 128 chunks)
        const int b = bid >> 7, c = bid & 127;
        const float* src = iV + ((size_t)(b * 2048 + c * 16)) * 1024 + tid * 4;
        float4 s = {0.f, 0.f, 0.f, 0.f};
        #pragma unroll
        for (int i = 0; i < 16; ++i) {
            const float4 v = *(const float4*)(src + (size_t)i * 1024);
            s.x += v.x; s.y += v.y; s.z += v.z; s.w += v.w;
        }
        *(float4*)(csum + ((size_t)(b * 128 + c)) * 1024 + tid * 4) = s;
    }
    grid_barrier(bar, 1 * GRID_BLOCKS);

    // ---------------- P1: scan + iQ cast ----------------
    {
        const int b = bid >> 7, c = bid & 127;
        const int d = tid * 4;
        const float* cs = csum + (size_t)b * 128 * 1024 + d;
        float4 a0 = {0,0,0,0}, a1 = {0,0,0,0}, a2 = {0,0,0,0}, a3 = {0,0,0,0};
        int cc = 0;
        for (; cc + 4 <= c; cc += 4) {
            const float4 v0 = *(const float4*)(cs + (size_t)(cc + 0) * 1024);
            const float4 v1 = *(const float4*)(cs + (size_t)(cc + 1) * 1024);
            const float4 v2 = *(const float4*)(cs + (size_t)(cc + 2) * 1024);
            const float4 v3 = *(const float4*)(cs + (size_t)(cc + 3) * 1024);
            a0.x += v0.x; a0.y += v0.y; a0.z += v0.z; a0.w += v0.w;
            a1.x += v1.x; a1.y += v1.y; a1.z += v1.z; a1.w += v1.w;
            a2.x += v2.x; a2.y += v2.y; a2.z += v2.z; a2.w += v2.w;
            a3.x += v3.x; a3.y += v3.y; a3.z += v3.z; a3.w += v3.w;
        }
        for (; cc < c; ++cc) {
            const float4 v = *(const float4*)(cs + (size_t)cc * 1024);
            a0.x += v.x; a0.y += v.y; a0.z += v.z; a0.w += v.w;
        }
        float4 acc;
        acc.x = (a0.x + a1.x) + (a2.x + a3.x);
        acc.y = (a0.y + a1.y) + (a2.y + a3.y);
        acc.z = (a0.z + a1.z) + (a2.z + a3.z);
        acc.w = (a0.w + a1.w) + (a2.w + a3.w);

        const size_t off = ((size_t)(b * 2048 + c * 16)) * 1024 + d;
        const float* src = iV + off;
        u16*         dst = regA + off;       // avg
        const int s0 = c * 16;
        #pragma unroll
        for (int i = 0; i < 16; ++i) {
            const float4 v = *(const float4*)(src + (size_t)i * 1024);
            acc.x += v.x; acc.y += v.y; acc.z += v.z; acc.w += v.w;
            const float inv = 1.0f / (float)(s0 + i + 1);
            ushort4 o;
            o.x = f2b(acc.x * inv); o.y = f2b(acc.y * inv);
            o.z = f2b(acc.z * inv); o.w = f2b(acc.w * inv);
            *(ushort4*)(dst + (size_t)i * 1024) = o;
        }
        // iQ f32 -> bf16
        const float4* iq4 = (const float4*)iQ;
        ushort4* qb4 = (ushort4*)iQb;
        for (int j = bid * 256 + tid; j < (8192 * 1024 / 4); j += GRID_BLOCKS * 256) {
            const float4 v = iq4[j];
            ushort4 o;
            o.x = f2b(v.x); o.y = f2b(v.y); o.z = f2b(v.z); o.w = f2b(v.w);
            qb4[j] = o;
        }
    }
    grid_barrier(bar, 2 * GRID_BLOCKS);

    // ---------------- P2: gemm1 ----------------
    gemm_body<0>(regA, W1t, b1, h, 1024, 1024, (bid >> 3) * 128, (bid & 7) * 128, smem);
    grid_barrier(bar, 3 * GRID_BLOCKS);

    // ---------------- P3: gemm2 (ffn -> regA) ----------------
    gemm_body<1>(h, W2t, b2, regA, 1024, 1024, (bid >> 3) * 128, (bid & 7) * 128, smem);
    grid_barrier(bar, 4 * GRID_BLOCKS);

    // ---------------- P4: gate ----------------
    gate_body(iQb, regA, Wgt, bg, iQ, out, (bid >> 3) * 128, (bid & 7) * 128, smem);
}

// ---------------------------------------------------------------------------
extern "C" void kernel_launch(void* const* d_in, const int* in_sizes, int n_in,
                              void* d_out, int out_size, void* d_ws, size_t ws_size,
                              hipStream_t stream) {
    const int D = 1024, D2 = 2048;
    const int M = 8192;

    const float* iQ = (const float*)d_in[0];
    const float* iV = (const float*)d_in[1];
    const float* W1 = (const float*)d_in[2];
    const float* b1 = (const float*)d_in[3];
    const float* W2 = (const float*)d_in[4];
    const float* b2 = (const float*)d_in[5];
    const float* Wg = (const float*)d_in[6];
    const float* bg = (const float*)d_in[7];
    float* out = (float*)d_out;

    // workspace (62 MB)
    u16*   regA = (u16*)d_ws;                      // avg -> ffn  (16 MB)
    u16*   h    = regA + (size_t)M * D;            //             (16 MB)
    u16*   iQb  = h    + (size_t)M * D;            //             (16 MB)
    u16*   W1t  = iQb  + (size_t)M * D;            //             ( 2 MB)
    u16*   W2t  = W1t  + (size_t)D * D;            //             ( 2 MB)
    u16*   Wgt  = W2t  + (size_t)D * D;            //             ( 8 MB)
    float* csum = (float*)(Wgt + (size_t)D2 * D2); // 4*128*1024  ( 2 MB)
    u32*   bar  = (u32*)(csum + (size_t)4 * 128 * 1024);

    hipMemsetAsync(bar, 0, 64, stream);
    fused_kernel<<<GRID_BLOCKS, 256, 0, stream>>>(
        iQ, iV, W1, b1, W2, b2, Wg, bg, out,
        regA, h, iQb, W1t, W2t, Wgt, csum, bar);
}